// Round 1
// baseline (141.431 us; speedup 1.0000x reference)
//
#include <hip/hip_runtime.h>
#include <math.h>

// Weighted Kabsch: B=4096 batches, N=1024 points.
// Kernel 1: per-batch single-pass reduction of 16 scalars
//   (wsum, sum(w*src_i), sum(w*corr_j), M_ij = sum(w*src_i*corr_j))
//   H_ij = M_ij - sum(w*src_i)*sum(w*corr_j)/wsum   (algebraic centering)
// Kernel 2: one lane per batch -> Jacobi eigensolve of H^T H (double),
//   U from H*V, R = v0 u0^T + v1 u1^T + det(V) v2 u2^T, t = c2 - R s2.

__device__ __forceinline__ float wred(float v) {
#pragma unroll
    for (int o = 32; o > 0; o >>= 1) v += __shfl_down(v, o);
    return v;
}

__global__ __launch_bounds__(256) void wsvd_reduce(
    const float* __restrict__ src, const float* __restrict__ corr,
    const float* __restrict__ wgt, float* __restrict__ sums)
{
    const int wave = threadIdx.x >> 6;
    const int lane = threadIdx.x & 63;
    const int b = blockIdx.x * 4 + wave;          // one wave per batch

    const float4* W = reinterpret_cast<const float4*>(wgt  + (size_t)b * 1024);
    const float4* S = reinterpret_cast<const float4*>(src  + (size_t)b * 3072);
    const float4* C = reinterpret_cast<const float4*>(corr + (size_t)b * 3072);

    float wsum = 0.f, ws0 = 0.f, ws1 = 0.f, ws2 = 0.f;
    float wc0 = 0.f, wc1 = 0.f, wc2 = 0.f;
    float m00 = 0.f, m01 = 0.f, m02 = 0.f;
    float m10 = 0.f, m11 = 0.f, m12 = 0.f;
    float m20 = 0.f, m21 = 0.f, m22 = 0.f;

#pragma unroll
    for (int k = 0; k < 4; ++k) {
        const int idx = lane + 64 * k;            // 256 float4 per row of 1024
        float4 wv = W[idx];
        float4 a0 = S[idx], a1 = S[idx + 256], a2 = S[idx + 512];
        float4 b0 = C[idx], b1 = C[idx + 256], b2 = C[idx + 512];
#define PROC(f) { \
        float w_ = wv.f; \
        float t0 = w_ * a0.f, t1 = w_ * a1.f, t2 = w_ * a2.f; \
        wsum += w_; ws0 += t0; ws1 += t1; ws2 += t2; \
        wc0 += w_ * b0.f; wc1 += w_ * b1.f; wc2 += w_ * b2.f; \
        m00 += t0 * b0.f; m01 += t0 * b1.f; m02 += t0 * b2.f; \
        m10 += t1 * b0.f; m11 += t1 * b1.f; m12 += t1 * b2.f; \
        m20 += t2 * b0.f; m21 += t2 * b1.f; m22 += t2 * b2.f; }
        PROC(x) PROC(y) PROC(z) PROC(w)
#undef PROC
    }

    wsum = wred(wsum);
    ws0 = wred(ws0); ws1 = wred(ws1); ws2 = wred(ws2);
    wc0 = wred(wc0); wc1 = wred(wc1); wc2 = wred(wc2);
    m00 = wred(m00); m01 = wred(m01); m02 = wred(m02);
    m10 = wred(m10); m11 = wred(m11); m12 = wred(m12);
    m20 = wred(m20); m21 = wred(m21); m22 = wred(m22);

    if (lane == 0) {
        float4* o = reinterpret_cast<float4*>(sums + (size_t)b * 16);
        o[0] = make_float4(wsum, ws0, ws1, ws2);
        o[1] = make_float4(wc0, wc1, wc2, m00);
        o[2] = make_float4(m01, m02, m10, m11);
        o[3] = make_float4(m12, m20, m21, m22);
    }
}

__global__ __launch_bounds__(256) void wsvd_solve(
    const float* __restrict__ sums, float* __restrict__ R_out,
    float* __restrict__ t_out, int B)
{
    const int b = blockIdx.x * blockDim.x + threadIdx.x;
    if (b >= B) return;

    const float4* p = reinterpret_cast<const float4*>(sums + (size_t)b * 16);
    float4 q0 = p[0], q1 = p[1], q2 = p[2], q3 = p[3];

    double wsum = q0.x;
    double ws0 = q0.y, ws1 = q0.z, ws2 = q0.w;
    double wc0 = q1.x, wc1 = q1.y, wc2 = q1.z;
    double m00 = q1.w, m01 = q2.x, m02 = q2.y;
    double m10 = q2.z, m11 = q2.w, m12 = q3.x;
    double m20 = q3.y, m21 = q3.z, m22 = q3.w;

    double inv = 1.0 / wsum;
    // centroids
    double s2x = ws0 * inv, s2y = ws1 * inv, s2z = ws2 * inv;
    double c2x = wc0 * inv, c2y = wc1 * inv, c2z = wc2 * inv;
    // H = M - ws * wc^T / wsum
    double h00 = m00 - ws0 * wc0 * inv, h01 = m01 - ws0 * wc1 * inv, h02 = m02 - ws0 * wc2 * inv;
    double h10 = m10 - ws1 * wc0 * inv, h11 = m11 - ws1 * wc1 * inv, h12 = m12 - ws1 * wc2 * inv;
    double h20 = m20 - ws2 * wc0 * inv, h21 = m21 - ws2 * wc1 * inv, h22 = m22 - ws2 * wc2 * inv;

    // A = H^T H (symmetric)
    double a00 = h00 * h00 + h10 * h10 + h20 * h20;
    double a11 = h01 * h01 + h11 * h11 + h21 * h21;
    double a22 = h02 * h02 + h12 * h12 + h22 * h22;
    double a01 = h00 * h01 + h10 * h11 + h20 * h21;
    double a02 = h00 * h02 + h10 * h12 + h20 * h22;
    double a12 = h01 * h02 + h11 * h12 + h21 * h22;

    // Jacobi eigensolve: A = V diag(l) V^T.  All scalars, no indexed arrays.
    double v00 = 1.0, v01 = 0.0, v02 = 0.0;
    double v10 = 0.0, v11 = 1.0, v12 = 0.0;
    double v20 = 0.0, v21 = 0.0, v22 = 1.0;

#define ROT(app, aqq, apq, apr, aqr, vp0, vq0, vp1, vq1, vp2, vq2) { \
    double apq_ = apq; \
    double cc, ss, tt; \
    if (fabs(apq_) > 1e-300) { \
        double tau = (aqq - app) / (2.0 * apq_); \
        tt = copysign(1.0, tau) / (fabs(tau) + sqrt(1.0 + tau * tau)); \
        cc = 1.0 / sqrt(1.0 + tt * tt); ss = tt * cc; \
    } else { tt = 0.0; cc = 1.0; ss = 0.0; } \
    app -= tt * apq_; aqq += tt * apq_; apq = 0.0; \
    { double pr = apr, qr = aqr; apr = cc * pr - ss * qr; aqr = ss * pr + cc * qr; } \
    { double t0_ = vp0; vp0 = cc * t0_ - ss * vq0; vq0 = ss * t0_ + cc * vq0; } \
    { double t0_ = vp1; vp1 = cc * t0_ - ss * vq1; vq1 = ss * t0_ + cc * vq1; } \
    { double t0_ = vp2; vp2 = cc * t0_ - ss * vq2; vq2 = ss * t0_ + cc * vq2; } }

    for (int sweep = 0; sweep < 6; ++sweep) {
        ROT(a00, a11, a01, a02, a12, v00, v01, v10, v11, v20, v21)  // (p,q)=(0,1)
        ROT(a00, a22, a02, a01, a12, v00, v02, v10, v12, v20, v22)  // (0,2)
        ROT(a11, a22, a12, a01, a02, v01, v02, v11, v12, v21, v22)  // (1,2)
    }
#undef ROT

    // sort eigenpairs descending (columns of V)
    double l0 = a00, l1 = a11, l2 = a22;
#define CSWAP(li, lj, x0, y0, x1, y1, x2, y2) if (li < lj) { double t_; \
    t_ = li; li = lj; lj = t_; t_ = x0; x0 = y0; y0 = t_; \
    t_ = x1; x1 = y1; y1 = t_; t_ = x2; x2 = y2; y2 = t_; }
    CSWAP(l0, l1, v00, v01, v10, v11, v20, v21)
    CSWAP(l0, l2, v00, v02, v10, v12, v20, v22)
    CSWAP(l1, l2, v01, v02, v11, v12, v21, v22)
#undef CSWAP

    // u0 = normalize(H v0)
    double u0x = h00 * v00 + h01 * v10 + h02 * v20;
    double u0y = h10 * v00 + h11 * v10 + h12 * v20;
    double u0z = h20 * v00 + h21 * v10 + h22 * v20;
    double n0 = sqrt(u0x * u0x + u0y * u0y + u0z * u0z);
    if (n0 > 1e-300) { double r = 1.0 / n0; u0x *= r; u0y *= r; u0z *= r; }
    else { u0x = 1.0; u0y = 0.0; u0z = 0.0; }

    // u1 = normalize(H v1 - (u0 . H v1) u0)
    double u1x = h00 * v01 + h01 * v11 + h02 * v21;
    double u1y = h10 * v01 + h11 * v11 + h12 * v21;
    double u1z = h20 * v01 + h21 * v11 + h22 * v21;
    double dp = u0x * u1x + u0y * u1y + u0z * u1z;
    u1x -= dp * u0x; u1y -= dp * u0y; u1z -= dp * u0z;
    double n1 = sqrt(u1x * u1x + u1y * u1y + u1z * u1z);
    if (n1 > 1e-300) { double r = 1.0 / n1; u1x *= r; u1y *= r; u1z *= r; }
    else {
        // any unit vector orthogonal to u0
        if (fabs(u0x) < 0.9) { u1x = 0.0; u1y = u0z; u1z = -u0y; }
        else                 { u1x = -u0z; u1y = 0.0; u1z = u0x; }
        double r = 1.0 / sqrt(u1x * u1x + u1y * u1y + u1z * u1z);
        u1x *= r; u1y *= r; u1z *= r;
    }

    // u2 = u0 x u1  (det(U) = +1 by construction)
    double u2x = u0y * u1z - u0z * u1y;
    double u2y = u0z * u1x - u0x * u1z;
    double u2z = u0x * u1y - u0y * u1x;

    double detV = v00 * (v11 * v22 - v12 * v21)
                - v01 * (v10 * v22 - v12 * v20)
                + v02 * (v10 * v21 - v11 * v20);
    double d = (detV >= 0.0) ? 1.0 : -1.0;

    // R[i][j] = v[i][0] u0[j] + v[i][1] u1[j] + d v[i][2] u2[j]
    double r00 = v00 * u0x + v01 * u1x + d * v02 * u2x;
    double r01 = v00 * u0y + v01 * u1y + d * v02 * u2y;
    double r02 = v00 * u0z + v01 * u1z + d * v02 * u2z;
    double r10 = v10 * u0x + v11 * u1x + d * v12 * u2x;
    double r11 = v10 * u0y + v11 * u1y + d * v12 * u2y;
    double r12 = v10 * u0z + v11 * u1z + d * v12 * u2z;
    double r20 = v20 * u0x + v21 * u1x + d * v22 * u2x;
    double r21 = v20 * u0y + v21 * u1y + d * v22 * u2y;
    double r22 = v20 * u0z + v21 * u1z + d * v22 * u2z;

    // t = c2 - R s2
    double tx = c2x - (r00 * s2x + r01 * s2y + r02 * s2z);
    double ty = c2y - (r10 * s2x + r11 * s2y + r12 * s2z);
    double tz = c2z - (r20 * s2x + r21 * s2y + r22 * s2z);

    float* Ro = R_out + (size_t)b * 9;
    Ro[0] = (float)r00; Ro[1] = (float)r01; Ro[2] = (float)r02;
    Ro[3] = (float)r10; Ro[4] = (float)r11; Ro[5] = (float)r12;
    Ro[6] = (float)r20; Ro[7] = (float)r21; Ro[8] = (float)r22;
    float* To = t_out + (size_t)b * 3;
    To[0] = (float)tx; To[1] = (float)ty; To[2] = (float)tz;
}

extern "C" void kernel_launch(void* const* d_in, const int* in_sizes, int n_in,
                              void* d_out, int out_size, void* d_ws, size_t ws_size,
                              hipStream_t stream) {
    const float* src  = (const float*)d_in[0];
    const float* corr = (const float*)d_in[1];
    const float* wgt  = (const float*)d_in[2];
    float* out = (float*)d_out;

    const int N = 1024;                       // fixed by problem spec
    const int B = in_sizes[2] / N;            // weight is (B,1,N)
    float* sums = (float*)d_ws;               // B*16 floats = 256 KB

    wsvd_reduce<<<B / 4, 256, 0, stream>>>(src, corr, wgt, sums);
    wsvd_solve<<<(B + 255) / 256, 256, 0, stream>>>(sums, out, out + (size_t)B * 9, B);
}

// Round 4
// 141.170 us; speedup vs baseline: 1.0018x; 1.0018x over previous
//
#include <hip/hip_runtime.h>
#include <math.h>

// Weighted Kabsch: B=4096 batches, N=1024 points.
// Kernel 1 (memory-bound): ONE BLOCK PER BATCH. 256 threads; each thread
//   issues 7 independent float4 loads (w, 3 src rows, 3 corr rows) covering
//   4 consecutive elements, accumulates 16 scalars, then 64-lane shuffle
//   reduce + 4-wave LDS combine. Max memory-level parallelism.
// Kernel 2 (tiny): one lane per batch -> Jacobi eigensolve of H^T H (double),
//   U from H*V, R = v0 u0^T + v1 u1^T + det(V) v2 u2^T, t = c2 - R s2.

__device__ __forceinline__ float wred64(float v) {
#pragma unroll
    for (int o = 32; o > 0; o >>= 1) v += __shfl_down(v, o);
    return v;
}

__global__ __launch_bounds__(256) void wsvd_reduce(
    const float* __restrict__ src, const float* __restrict__ corr,
    const float* __restrict__ wgt, float* __restrict__ sums)
{
    const int b = blockIdx.x;                 // one block per batch
    const int t = threadIdx.x;                // 0..255, one float4 column each
    const int wave = t >> 6, lane = t & 63;

    const float4* W = reinterpret_cast<const float4*>(wgt  + (size_t)b * 1024);
    const float4* S = reinterpret_cast<const float4*>(src  + (size_t)b * 3072);
    const float4* C = reinterpret_cast<const float4*>(corr + (size_t)b * 3072);

    // 7 independent coalesced 16B loads, all issued before any use.
    float4 wv = W[t];
    float4 a0 = S[t], a1 = S[t + 256], a2 = S[t + 512];
    float4 b0 = C[t], b1 = C[t + 256], b2 = C[t + 512];

    float wsum = 0.f, ws0 = 0.f, ws1 = 0.f, ws2 = 0.f;
    float wc0 = 0.f, wc1 = 0.f, wc2 = 0.f;
    float m00 = 0.f, m01 = 0.f, m02 = 0.f;
    float m10 = 0.f, m11 = 0.f, m12 = 0.f;
    float m20 = 0.f, m21 = 0.f, m22 = 0.f;

#define PROC(f) { \
    float w_ = wv.f; \
    float t0 = w_ * a0.f, t1 = w_ * a1.f, t2 = w_ * a2.f; \
    wsum += w_; ws0 += t0; ws1 += t1; ws2 += t2; \
    wc0 += w_ * b0.f; wc1 += w_ * b1.f; wc2 += w_ * b2.f; \
    m00 += t0 * b0.f; m01 += t0 * b1.f; m02 += t0 * b2.f; \
    m10 += t1 * b0.f; m11 += t1 * b1.f; m12 += t1 * b2.f; \
    m20 += t2 * b0.f; m21 += t2 * b1.f; m22 += t2 * b2.f; }
    PROC(x) PROC(y) PROC(z) PROC(w)
#undef PROC

    wsum = wred64(wsum);
    ws0 = wred64(ws0); ws1 = wred64(ws1); ws2 = wred64(ws2);
    wc0 = wred64(wc0); wc1 = wred64(wc1); wc2 = wred64(wc2);
    m00 = wred64(m00); m01 = wred64(m01); m02 = wred64(m02);
    m10 = wred64(m10); m11 = wred64(m11); m12 = wred64(m12);
    m20 = wred64(m20); m21 = wred64(m21); m22 = wred64(m22);

    __shared__ float sm[4][16];
    if (lane == 0) {
        float* o = sm[wave];
        o[0] = wsum; o[1] = ws0; o[2] = ws1; o[3] = ws2;
        o[4] = wc0;  o[5] = wc1; o[6] = wc2; o[7] = m00;
        o[8] = m01;  o[9] = m02; o[10] = m10; o[11] = m11;
        o[12] = m12; o[13] = m20; o[14] = m21; o[15] = m22;
    }
    __syncthreads();
    if (t < 16) {
        float s = sm[0][t] + sm[1][t] + sm[2][t] + sm[3][t];
        sums[(size_t)b * 16 + t] = s;
    }
}

__global__ __launch_bounds__(64) void wsvd_solve(
    const float* __restrict__ sums, float* __restrict__ R_out,
    float* __restrict__ t_out, int B)
{
    const int b = blockIdx.x * blockDim.x + threadIdx.x;
    if (b >= B) return;

    const float4* p = reinterpret_cast<const float4*>(sums + (size_t)b * 16);
    float4 q0 = p[0], q1 = p[1], q2 = p[2], q3 = p[3];

    double wsum = q0.x;
    double ws0 = q0.y, ws1 = q0.z, ws2 = q0.w;
    double wc0 = q1.x, wc1 = q1.y, wc2 = q1.z;
    double m00 = q1.w, m01 = q2.x, m02 = q2.y;
    double m10 = q2.z, m11 = q2.w, m12 = q3.x;
    double m20 = q3.y, m21 = q3.z, m22 = q3.w;

    double inv = 1.0 / wsum;
    double s2x = ws0 * inv, s2y = ws1 * inv, s2z = ws2 * inv;
    double c2x = wc0 * inv, c2y = wc1 * inv, c2z = wc2 * inv;
    double h00 = m00 - ws0 * wc0 * inv, h01 = m01 - ws0 * wc1 * inv, h02 = m02 - ws0 * wc2 * inv;
    double h10 = m10 - ws1 * wc0 * inv, h11 = m11 - ws1 * wc1 * inv, h12 = m12 - ws1 * wc2 * inv;
    double h20 = m20 - ws2 * wc0 * inv, h21 = m21 - ws2 * wc1 * inv, h22 = m22 - ws2 * wc2 * inv;

    // A = H^T H (symmetric)
    double a00 = h00 * h00 + h10 * h10 + h20 * h20;
    double a11 = h01 * h01 + h11 * h11 + h21 * h21;
    double a22 = h02 * h02 + h12 * h12 + h22 * h22;
    double a01 = h00 * h01 + h10 * h11 + h20 * h21;
    double a02 = h00 * h02 + h10 * h12 + h20 * h22;
    double a12 = h01 * h02 + h11 * h12 + h21 * h22;

    // Jacobi eigensolve: A = V diag(l) V^T. All scalars, no indexed arrays.
    double v00 = 1.0, v01 = 0.0, v02 = 0.0;
    double v10 = 0.0, v11 = 1.0, v12 = 0.0;
    double v20 = 0.0, v21 = 0.0, v22 = 1.0;

#define ROT(app, aqq, apq, apr, aqr, vp0, vq0, vp1, vq1, vp2, vq2) { \
    double apq_ = apq; \
    double cc, ss, tt; \
    if (fabs(apq_) > 1e-300) { \
        double tau = (aqq - app) / (2.0 * apq_); \
        tt = copysign(1.0, tau) / (fabs(tau) + sqrt(1.0 + tau * tau)); \
        cc = 1.0 / sqrt(1.0 + tt * tt); ss = tt * cc; \
    } else { tt = 0.0; cc = 1.0; ss = 0.0; } \
    app -= tt * apq_; aqq += tt * apq_; apq = 0.0; \
    { double pr = apr, qr = aqr; apr = cc * pr - ss * qr; aqr = ss * pr + cc * qr; } \
    { double t0_ = vp0; vp0 = cc * t0_ - ss * vq0; vq0 = ss * t0_ + cc * vq0; } \
    { double t0_ = vp1; vp1 = cc * t0_ - ss * vq1; vq1 = ss * t0_ + cc * vq1; } \
    { double t0_ = vp2; vp2 = cc * t0_ - ss * vq2; vq2 = ss * t0_ + cc * vq2; } }

    for (int sweep = 0; sweep < 5; ++sweep) {
        ROT(a00, a11, a01, a02, a12, v00, v01, v10, v11, v20, v21)  // (p,q)=(0,1)
        ROT(a00, a22, a02, a01, a12, v00, v02, v10, v12, v20, v22)  // (0,2)
        ROT(a11, a22, a12, a01, a02, v01, v02, v11, v12, v21, v22)  // (1,2)
    }
#undef ROT

    // sort eigenpairs descending (columns of V)
    double l0 = a00, l1 = a11, l2 = a22;
#define CSWAP(li, lj, x0, y0, x1, y1, x2, y2) if (li < lj) { double t_; \
    t_ = li; li = lj; lj = t_; t_ = x0; x0 = y0; y0 = t_; \
    t_ = x1; x1 = y1; y1 = t_; t_ = x2; x2 = y2; y2 = t_; }
    CSWAP(l0, l1, v00, v01, v10, v11, v20, v21)
    CSWAP(l0, l2, v00, v02, v10, v12, v20, v22)
    CSWAP(l1, l2, v01, v02, v11, v12, v21, v22)
#undef CSWAP

    // u0 = normalize(H v0)
    double u0x = h00 * v00 + h01 * v10 + h02 * v20;
    double u0y = h10 * v00 + h11 * v10 + h12 * v20;
    double u0z = h20 * v00 + h21 * v10 + h22 * v20;
    double n0 = sqrt(u0x * u0x + u0y * u0y + u0z * u0z);
    if (n0 > 1e-300) { double r = 1.0 / n0; u0x *= r; u0y *= r; u0z *= r; }
    else { u0x = 1.0; u0y = 0.0; u0z = 0.0; }

    // u1 = normalize(H v1 - (u0 . H v1) u0)
    double u1x = h00 * v01 + h01 * v11 + h02 * v21;
    double u1y = h10 * v01 + h11 * v11 + h12 * v21;
    double u1z = h20 * v01 + h21 * v11 + h22 * v21;
    double dp = u0x * u1x + u0y * u1y + u0z * u1z;
    u1x -= dp * u0x; u1y -= dp * u0y; u1z -= dp * u0z;
    double n1 = sqrt(u1x * u1x + u1y * u1y + u1z * u1z);
    if (n1 > 1e-300) { double r = 1.0 / n1; u1x *= r; u1y *= r; u1z *= r; }
    else {
        if (fabs(u0x) < 0.9) { u1x = 0.0; u1y = u0z; u1z = -u0y; }
        else                 { u1x = -u0z; u1y = 0.0; u1z = u0x; }
        double r = 1.0 / sqrt(u1x * u1x + u1y * u1y + u1z * u1z);
        u1x *= r; u1y *= r; u1z *= r;
    }

    // u2 = u0 x u1  (det(U) = +1 by construction)
    double u2x = u0y * u1z - u0z * u1y;
    double u2y = u0z * u1x - u0x * u1z;
    double u2z = u0x * u1y - u0y * u1x;

    double detV = v00 * (v11 * v22 - v12 * v21)
                - v01 * (v10 * v22 - v12 * v20)
                + v02 * (v10 * v21 - v11 * v20);
    double d = (detV >= 0.0) ? 1.0 : -1.0;

    // R[i][j] = v[i][0] u0[j] + v[i][1] u1[j] + d v[i][2] u2[j]
    double r00 = v00 * u0x + v01 * u1x + d * v02 * u2x;
    double r01 = v00 * u0y + v01 * u1y + d * v02 * u2y;
    double r02 = v00 * u0z + v01 * u1z + d * v02 * u2z;
    double r10 = v10 * u0x + v11 * u1x + d * v12 * u2x;
    double r11 = v10 * u0y + v11 * u1y + d * v12 * u2y;
    double r12 = v10 * u0z + v11 * u1z + d * v12 * u2z;
    double r20 = v20 * u0x + v21 * u1x + d * v22 * u2x;
    double r21 = v20 * u0y + v21 * u1y + d * v22 * u2y;
    double r22 = v20 * u0z + v21 * u1z + d * v22 * u2z;

    // t = c2 - R s2
    double tx = c2x - (r00 * s2x + r01 * s2y + r02 * s2z);
    double ty = c2y - (r10 * s2x + r11 * s2y + r12 * s2z);
    double tz = c2z - (r20 * s2x + r21 * s2y + r22 * s2z);

    float* Ro = R_out + (size_t)b * 9;
    Ro[0] = (float)r00; Ro[1] = (float)r01; Ro[2] = (float)r02;
    Ro[3] = (float)r10; Ro[4] = (float)r11; Ro[5] = (float)r12;
    Ro[6] = (float)r20; Ro[7] = (float)r21; Ro[8] = (float)r22;
    float* To = t_out + (size_t)b * 3;
    To[0] = (float)tx; To[1] = (float)ty; To[2] = (float)tz;
}

extern "C" void kernel_launch(void* const* d_in, const int* in_sizes, int n_in,
                              void* d_out, int out_size, void* d_ws, size_t ws_size,
                              hipStream_t stream) {
    const float* src  = (const float*)d_in[0];
    const float* corr = (const float*)d_in[1];
    const float* wgt  = (const float*)d_in[2];
    float* out = (float*)d_out;

    const int N = 1024;                       // fixed by problem spec
    const int B = in_sizes[2] / N;            // weight is (B,1,N)
    float* sums = (float*)d_ws;               // B*16 floats = 256 KB

    wsvd_reduce<<<B, 256, 0, stream>>>(src, corr, wgt, sums);
    wsvd_solve<<<(B + 63) / 64, 64, 0, stream>>>(sums, out, out + (size_t)B * 9, B);
}